// Round 8
// baseline (988.356 us; speedup 1.0000x reference)
//
#include <hip/hip_runtime.h>
#include <math.h>
#include <stdint.h>

// Problem dims
#define B_    128
#define T_    250
#define IN_   700
#define INP_  704    // padded to 32
#define H_    512
#define OUT_  20
#define BR_   4
#define HB_   2048   // H_*BR_
#define WARM_ 10
#define VTH_  1.0f

typedef __attribute__((ext_vector_type(8)))  _Float16 half8;
typedef __attribute__((ext_vector_type(4)))  float f32x4;
typedef __attribute__((ext_vector_type(16))) float f32x16;
typedef __attribute__((ext_vector_type(4)))  int i32x4;
typedef __attribute__((ext_vector_type(16))) int i32x16;
typedef const __attribute__((address_space(1))) void* gptr_t;
typedef __attribute__((address_space(3))) void* lptr_t;

// ---------------- prep: split fp32 -> hi/lo fp16 planes (layer 1) ----------------
__global__ __launch_bounds__(256)
void w1prep_kernel(const float* __restrict__ W, const float* __restrict__ M,
                   _Float16* __restrict__ w0, _Float16* __restrict__ w1) {
    int i = blockIdx.x * 256 + threadIdx.x;           // over HB_*INP_
    if (i >= HB_ * INP_) return;
    int r = i / INP_, c = i - r * INP_;
    float v = (c < IN_) ? W[(size_t)r * IN_ + c] * M[(size_t)r * IN_ + c] : 0.f;
    _Float16 h0 = (_Float16)v;
    w0[i] = h0;
    w1[i] = (_Float16)(v - (float)h0);
}

// ---------------- prep: layer-2 weights -> 3 signed radix-256 i8 planes, scale 2^26 ----------------
__global__ __launch_bounds__(256)
void w2prep_kernel(const float* __restrict__ W, const float* __restrict__ M,
                   int8_t* __restrict__ p2, int8_t* __restrict__ p1,
                   int8_t* __restrict__ p0) {
    int i = blockIdx.x * 256 + threadIdx.x;           // over HB_*H_
    if (i >= HB_ * H_) return;
    float v = W[i] * M[i];
    int q = (int)lrintf(v * 67108864.f);              // |q| <= ~2.97e6
    int b0 = (int)(int8_t)(q & 0xFF);  q = (q - b0) >> 8;
    int b1 = (int)(int8_t)(q & 0xFF);  int b2 = (q - b1) >> 8;   // |b2| <= 46
    p0[i] = (int8_t)b0; p1[i] = (int8_t)b1; p2[i] = (int8_t)b2;
}

// ---------------- prep: readout weights -> hi/lo fp16 planes, n padded to 32 ----------------
__global__ __launch_bounds__(256)
void woprep_kernel(const float* __restrict__ Wo, _Float16* __restrict__ wo0,
                   _Float16* __restrict__ wo1) {
    int i = blockIdx.x * 256 + threadIdx.x;           // over 32*H_
    if (i >= 32 * H_) return;
    int n = i >> 9;
    float v = (n < OUT_) ? Wo[(size_t)n * H_ + (i & (H_ - 1))] : 0.f;
    _Float16 h0 = (_Float16)v;
    wo0[i] = h0;
    wo1[i] = (_Float16)(v - (float)h0);
}

// per-chunk x conversion: global rows (bb*T_+t0+tl) -> chunk-local [128*tc, INP_]
__global__ __launch_bounds__(256)
void convx_kernel(const float* __restrict__ x, _Float16* __restrict__ x0,
                  _Float16* __restrict__ x1, int t0, int tc, int ntot) {
    int i = blockIdx.x * 256 + threadIdx.x;
    if (i >= ntot) return;
    int r = i / INP_, c = i - r * INP_;
    int bb = r / tc, tl = r - bb * tc;
    float v = (c < IN_) ? x[((size_t)bb * T_ + t0 + tl) * IN_ + c] : 0.f;
    _Float16 h0 = (_Float16)v;
    x0[i] = h0;
    x1[i] = (_Float16)(v - (float)h0);
}

__global__ void zero_kernel(float* __restrict__ p, int n4) {
    int i = blockIdx.x * blockDim.x + threadIdx.x;
    if (i < n4) ((float4*)p)[i] = make_float4(0.f, 0.f, 0.f, 0.f);
}

// ---------------- L1 GEMM: 32x32x16 f16 MFMA, fragment-major LDS (conflict-free) ----------
// LDS tile = 8 blocks of 1 KB; block (rg,ks) at offset ((rg*2+ks)*512 halfs), position
// lane*8 halfs holds A[rg*32 + (lane&31)][k0 + ks*16 + (lane>>5)*8 ..+8].
// Fragment read for (wsel,mt,ks): base + ((wsel*2+mt)*2+ks)*512 + lane*8  -> stride-1, 0 conflicts.
__global__ __launch_bounds__(256)
void l1_gemm_kernel(const _Float16* __restrict__ x0, const _Float16* __restrict__ x1,
                    const _Float16* __restrict__ w0, const _Float16* __restrict__ w1,
                    const float* __restrict__ bias, float* __restrict__ C) {
    __shared__ alignas(16) _Float16 A0s[128 * 32];
    __shared__ alignas(16) _Float16 A1s[128 * 32];
    __shared__ alignas(16) _Float16 B0s[128 * 32];
    __shared__ alignas(16) _Float16 B1s[128 * 32];
    const int tid  = threadIdx.x;
    const int wave = tid >> 6, lane = tid & 63;
    const int bm = blockIdx.y * 128, bn = blockIdx.x * 128;

    // staging: wave -> (rg = wave>>1, ks = wave&1); lane -> (row rg*32+(lane&31), k ks*16+(lane>>5)*8)
    const int r5 = lane & 31, k5 = lane >> 5;
    const int srg = wave >> 1, sks = wave & 1;
    const size_t aoff0 = (size_t)(bm + srg * 32 + r5) * INP_ + sks * 16 + k5 * 8;
    const size_t aoff1 = aoff0 + (size_t)64 * INP_;
    const size_t boff0 = (size_t)(bn + srg * 32 + r5) * INP_ + sks * 16 + k5 * 8;
    const size_t boff1 = boff0 + (size_t)64 * INP_;
    const int lo0 = wave * 512, lo1 = 2048 + wave * 512;   // halfs

    const int wm = wave & 1, wn = wave >> 1;
    const int lh8 = lane * 8;

    f32x16 acc[2][2] = {};

    for (int kt = 0; kt < INP_ / 32; kt++) {
        const int k0 = kt * 32;
        __builtin_amdgcn_global_load_lds((gptr_t)(x0 + aoff0 + k0), (lptr_t)(A0s + lo0), 16, 0, 0);
        __builtin_amdgcn_global_load_lds((gptr_t)(x0 + aoff1 + k0), (lptr_t)(A0s + lo1), 16, 0, 0);
        __builtin_amdgcn_global_load_lds((gptr_t)(x1 + aoff0 + k0), (lptr_t)(A1s + lo0), 16, 0, 0);
        __builtin_amdgcn_global_load_lds((gptr_t)(x1 + aoff1 + k0), (lptr_t)(A1s + lo1), 16, 0, 0);
        __builtin_amdgcn_global_load_lds((gptr_t)(w0 + boff0 + k0), (lptr_t)(B0s + lo0), 16, 0, 0);
        __builtin_amdgcn_global_load_lds((gptr_t)(w0 + boff1 + k0), (lptr_t)(B0s + lo1), 16, 0, 0);
        __builtin_amdgcn_global_load_lds((gptr_t)(w1 + boff0 + k0), (lptr_t)(B1s + lo0), 16, 0, 0);
        __builtin_amdgcn_global_load_lds((gptr_t)(w1 + boff1 + k0), (lptr_t)(B1s + lo1), 16, 0, 0);
        __syncthreads();

        half8 a0f[2][2], a1f[2][2], b0f[2][2], b1f[2][2];   // [tile][kstep]
#pragma unroll
        for (int mt = 0; mt < 2; mt++)
#pragma unroll
            for (int ks = 0; ks < 2; ks++)
                a0f[mt][ks] = *(const half8*)&A0s[(((wm * 2 + mt) * 2 + ks)) * 512 + lh8];
#pragma unroll
        for (int nt = 0; nt < 2; nt++)
#pragma unroll
            for (int ks = 0; ks < 2; ks++)
                b0f[nt][ks] = *(const half8*)&B0s[(((wn * 2 + nt) * 2 + ks)) * 512 + lh8];
#pragma unroll
        for (int ks = 0; ks < 2; ks++)
#pragma unroll
            for (int mt = 0; mt < 2; mt++)
#pragma unroll
                for (int nt = 0; nt < 2; nt++)
                    acc[mt][nt] = __builtin_amdgcn_mfma_f32_32x32x16_f16(
                        a0f[mt][ks], b0f[nt][ks], acc[mt][nt], 0, 0, 0);
#pragma unroll
        for (int nt = 0; nt < 2; nt++)
#pragma unroll
            for (int ks = 0; ks < 2; ks++)
                b1f[nt][ks] = *(const half8*)&B1s[(((wn * 2 + nt) * 2 + ks)) * 512 + lh8];
#pragma unroll
        for (int ks = 0; ks < 2; ks++)
#pragma unroll
            for (int mt = 0; mt < 2; mt++)
#pragma unroll
                for (int nt = 0; nt < 2; nt++)
                    acc[mt][nt] = __builtin_amdgcn_mfma_f32_32x32x16_f16(
                        a0f[mt][ks], b1f[nt][ks], acc[mt][nt], 0, 0, 0);
#pragma unroll
        for (int mt = 0; mt < 2; mt++)
#pragma unroll
            for (int ks = 0; ks < 2; ks++)
                a1f[mt][ks] = *(const half8*)&A1s[(((wm * 2 + mt) * 2 + ks)) * 512 + lh8];
#pragma unroll
        for (int ks = 0; ks < 2; ks++)
#pragma unroll
            for (int mt = 0; mt < 2; mt++)
#pragma unroll
                for (int nt = 0; nt < 2; nt++)
                    acc[mt][nt] = __builtin_amdgcn_mfma_f32_32x32x16_f16(
                        a1f[mt][ks], b0f[nt][ks], acc[mt][nt], 0, 0, 0);
        __syncthreads();
    }

    // C/D: col=lane&31, row=(reg&3)+8*(reg>>2)+4*(lane>>5)
    const int col = lane & 31;
    const int rb  = 4 * (lane >> 5);
#pragma unroll
    for (int nt = 0; nt < 2; nt++) {
        const int gc = bn + wn * 64 + nt * 32 + col;
        const float bv = bias[gc];
#pragma unroll
        for (int mt = 0; mt < 2; mt++) {
#pragma unroll
            for (int reg = 0; reg < 16; reg++) {
                const int gr = bm + wm * 64 + mt * 32 + (reg & 3) + 8 * (reg >> 2) + rb;
                C[(size_t)gr * HB_ + gc] = acc[mt][nt][reg] + bv;
            }
        }
    }
}

// ---------------- i8 GEMM (layer 2): 32x32x32, fragment-major LDS, exact Horner ----------------
// LDS tile = 8 blocks of 1 KB; block (rg,ks) holds A[rg*32+(lane&31)][k0 + ks*32 + (lane>>5)*16 ..+16].
__global__ __launch_bounds__(256)
void mfma_i8_gemm_kernel(const int8_t* __restrict__ A,
                         const int8_t* __restrict__ p2, const int8_t* __restrict__ p1,
                         const int8_t* __restrict__ p0,
                         const float* __restrict__ bias, float* __restrict__ C) {
    __shared__ alignas(16) int8_t As[128 * 64];   // 8 KB, K-tile 64
    __shared__ alignas(16) int8_t Bs[128 * 64];
    const int tid  = threadIdx.x;
    const int wave = tid >> 6, lane = tid & 63;
    const int bm = blockIdx.y * 128, bn = blockIdx.x * 128;   // n-fastest

    const int r5 = lane & 31, k5 = lane >> 5;
    const int srg = wave >> 1, sks = wave & 1;
    const size_t aoff0 = (size_t)(bm + srg * 32 + r5) * H_ + sks * 32 + k5 * 16;
    const size_t aoff1 = aoff0 + (size_t)64 * H_;
    const size_t boff0 = (size_t)(bn + srg * 32 + r5) * H_ + sks * 32 + k5 * 16;
    const size_t boff1 = boff0 + (size_t)64 * H_;
    lptr_t lA0 = (lptr_t)(As + wave * 1024);
    lptr_t lA1 = (lptr_t)(As + 4096 + wave * 1024);
    lptr_t lB0 = (lptr_t)(Bs + wave * 1024);
    lptr_t lB1 = (lptr_t)(Bs + 4096 + wave * 1024);

    const int wm = wave & 1, wn = wave >> 1;
    const int lb16 = lane * 16;

    const int8_t* planes[3] = {p2, p1, p0};
    i32x16 acc[2][2] = {};

#pragma unroll
    for (int s = 0; s < 3; s++) {
        if (s) {
#pragma unroll
            for (int mt = 0; mt < 2; mt++)
#pragma unroll
                for (int nt = 0; nt < 2; nt++) acc[mt][nt] *= 256;  // exact, |acc|<1.6e9
        }
        const int8_t* pw = planes[s];
        for (int kt = 0; kt < H_ / 64; kt++) {
            const int k0 = kt * 64;
            __builtin_amdgcn_global_load_lds((gptr_t)(A  + aoff0 + k0), lA0, 16, 0, 0);
            __builtin_amdgcn_global_load_lds((gptr_t)(A  + aoff1 + k0), lA1, 16, 0, 0);
            __builtin_amdgcn_global_load_lds((gptr_t)(pw + boff0 + k0), lB0, 16, 0, 0);
            __builtin_amdgcn_global_load_lds((gptr_t)(pw + boff1 + k0), lB1, 16, 0, 0);
            __syncthreads();

            i32x4 af[2][2], bf[2][2];
#pragma unroll
            for (int mt = 0; mt < 2; mt++)
#pragma unroll
                for (int ks = 0; ks < 2; ks++)
                    af[mt][ks] = *(const i32x4*)&As[(((wm * 2 + mt) * 2 + ks)) * 1024 + lb16];
#pragma unroll
            for (int nt = 0; nt < 2; nt++)
#pragma unroll
                for (int ks = 0; ks < 2; ks++)
                    bf[nt][ks] = *(const i32x4*)&Bs[(((wn * 2 + nt) * 2 + ks)) * 1024 + lb16];
#pragma unroll
            for (int ks = 0; ks < 2; ks++)
#pragma unroll
                for (int mt = 0; mt < 2; mt++)
#pragma unroll
                    for (int nt = 0; nt < 2; nt++)
                        acc[mt][nt] = __builtin_amdgcn_mfma_i32_32x32x32_i8(
                            af[mt][ks], bf[nt][ks], acc[mt][nt], 0, 0, 0);
            __syncthreads();
        }
    }

    const float scale = 1.f / 67108864.f;
    const int col = lane & 31;
    const int rb  = 4 * (lane >> 5);
#pragma unroll
    for (int nt = 0; nt < 2; nt++) {
        const int gc = bn + wn * 64 + nt * 32 + col;
        const float bv = bias[gc];
#pragma unroll
        for (int mt = 0; mt < 2; mt++) {
#pragma unroll
            for (int reg = 0; reg < 16; reg++) {
                const int gr = bm + wm * 64 + mt * 32 + (reg & 3) + 8 * (reg >> 2) + rb;
                C[(size_t)gr * HB_ + gc] = (float)acc[mt][nt][reg] * scale + bv;
            }
        }
    }
}

// ---------------- per-(b,h) LIF scans over a time chunk (chunk-local I/O) ----------------
#define SCAN_BODY(SPIKE_STORE)                                                  \
    int idx = blockIdx.x * 256 + threadIdx.x;                                   \
    int b = idx >> 9;                                                           \
    int h = idx & (H_ - 1);                                                     \
    float alpha = 1.f / (1.f + expf(-tau_m[h]));                                \
    float4 tn = ((const float4*)tau_n)[h];                                      \
    float4 beta;                                                                \
    beta.x = 1.f / (1.f + expf(-tn.x));                                         \
    beta.y = 1.f / (1.f + expf(-tn.y));                                         \
    beta.z = 1.f / (1.f + expf(-tn.z));                                         \
    beta.w = 1.f / (1.f + expf(-tn.w));                                         \
    float4 d = ((const float4*)dst)[idx];                                       \
    float m = mst[idx];                                                         \
    float sp = spst[idx];                                                       \
    const float* cp = cur + (size_t)b * tc * HB_ + h * BR_;                     \
    for (int t = 0; t < tc; t++) {                                              \
        float4 c = *(const float4*)cp;                                          \
        cp += HB_;                                                              \
        d.x = beta.x * d.x + (1.f - beta.x) * c.x;                              \
        d.y = beta.y * d.y + (1.f - beta.y) * c.y;                              \
        d.z = beta.z * d.z + (1.f - beta.z) * c.z;                              \
        d.w = beta.w * d.w + (1.f - beta.w) * c.w;                              \
        float s4 = ((d.x + d.y) + d.z) + d.w;                                   \
        m = m * alpha + (1.f - alpha) * s4 - VTH_ * sp;                         \
        sp = (m > VTH_) ? 1.f : 0.f;                                            \
        SPIKE_STORE;                                                            \
    }                                                                           \
    ((float4*)dst)[idx] = d;                                                    \
    mst[idx] = m;                                                               \
    spst[idx] = sp;

__global__ __launch_bounds__(256)
void scan_i8_kernel(const float* __restrict__ cur, float* __restrict__ dst,
                    float* __restrict__ mst, float* __restrict__ spst,
                    int8_t* __restrict__ sout, const float* __restrict__ tau_m,
                    const float* __restrict__ tau_n, int tc) {
    SCAN_BODY(sout[((size_t)b * tc + t) * H_ + h] = (int8_t)(m > VTH_))
}

__global__ __launch_bounds__(256)
void scan_f16_kernel(const float* __restrict__ cur, float* __restrict__ dst,
                     float* __restrict__ mst, float* __restrict__ spst,
                     _Float16* __restrict__ sout, const float* __restrict__ tau_m,
                     const float* __restrict__ tau_n, int tc) {
    SCAN_BODY(sout[((size_t)b * tc + t) * H_ + h] = (_Float16)sp)
}

// ---------------- readout GEMM (MFMA 16x16): curo[b,t,o] = s2c . (wo0+wo1)^T + bo ----------------
__global__ __launch_bounds__(256)
void rdot_mfma_kernel(const _Float16* __restrict__ s2c, const _Float16* __restrict__ wo0,
                      const _Float16* __restrict__ wo1, const float* __restrict__ bo,
                      float* __restrict__ curo, int t0, int tc) {
    __shared__ alignas(16) _Float16 As[128 * 32];   // 8 KB
    __shared__ alignas(16) _Float16 B0s[32 * 32];   // 2 KB
    __shared__ alignas(16) _Float16 B1s[32 * 32];
    const int tid  = threadIdx.x;
    const int wave = tid >> 6, lane = tid & 63;
    const int bm = blockIdx.x * 128;

    const int    srow  = tid >> 2;
    const int    skoff = (tid & 3) * 8;
    const size_t aoff0 = (size_t)(bm + srow) * H_ + skoff;
    const size_t aoff1 = aoff0 + (size_t)64 * H_;
    lptr_t lA0 = (lptr_t)(As + wave * 512);
    lptr_t lA1 = (lptr_t)(As + 2048 + wave * 512);
    const _Float16* bsrc = (wave < 2) ? wo0 : wo1;
    const int bw = wave & 1;
    const size_t boff = (size_t)(bw * 16 + (lane >> 2)) * H_ + (lane & 3) * 8;
    lptr_t lB = (lptr_t)(((wave < 2) ? B0s : B1s) + bw * 512);

    const int fr = lane & 15;
    const int fk = (lane >> 4) * 8;

    f32x4 acc[2][2] = {};

    for (int kt = 0; kt < H_ / 32; kt++) {
        const int k0 = kt * 32;
        __builtin_amdgcn_global_load_lds((gptr_t)(s2c + aoff0 + k0), lA0, 16, 0, 0);
        __builtin_amdgcn_global_load_lds((gptr_t)(s2c + aoff1 + k0), lA1, 16, 0, 0);
        __builtin_amdgcn_global_load_lds((gptr_t)(bsrc + boff + k0), lB, 16, 0, 0);
        __syncthreads();

        half8 af[2], b0[2], b1[2];
#pragma unroll
        for (int mi = 0; mi < 2; mi++)
            af[mi] = *(const half8*)&As[(wave * 32 + mi * 16 + fr) * 32 + fk];
#pragma unroll
        for (int ni = 0; ni < 2; ni++) {
            b0[ni] = *(const half8*)&B0s[(ni * 16 + fr) * 32 + fk];
            b1[ni] = *(const half8*)&B1s[(ni * 16 + fr) * 32 + fk];
        }
#pragma unroll
        for (int mi = 0; mi < 2; mi++)
#pragma unroll
            for (int ni = 0; ni < 2; ni++) {
                acc[mi][ni] = __builtin_amdgcn_mfma_f32_16x16x32_f16(af[mi], b0[ni], acc[mi][ni], 0, 0, 0);
                acc[mi][ni] = __builtin_amdgcn_mfma_f32_16x16x32_f16(af[mi], b1[ni], acc[mi][ni], 0, 0, 0);
            }
        __syncthreads();
    }

    const int cc = lane & 15;
    const int cr = (lane >> 4) * 4;
#pragma unroll
    for (int ni = 0; ni < 2; ni++) {
        const int gc = ni * 16 + cc;
        if (gc < OUT_) {
            const float bv = bo[gc];
#pragma unroll
            for (int mi = 0; mi < 2; mi++) {
#pragma unroll
                for (int r = 0; r < 4; r++) {
                    const int gr = bm + wave * 32 + mi * 16 + cr + r;
                    const int bb = gr / tc, tl = gr - bb * tc;
                    curo[((size_t)bb * T_ + t0 + tl) * OUT_ + gc] = acc[mi][ni][r] + bv;
                }
            }
        }
    }
}

// ---------------- parallel readout: segmented scan + t-parallel softmax-sum ----------------
#define RT_SEG 12
#define RT_LEN 21   // 12*21 = 252 >= 250

__global__ __launch_bounds__(256)
void readout_kernel(const float* __restrict__ curo, const float* __restrict__ tau_mo,
                    float* __restrict__ out) {
    __shared__ float moS[T_ * OUT_];          // 20 KB
    __shared__ float segA[RT_SEG][OUT_];
    __shared__ float segU[RT_SEG][OUT_];
    __shared__ float pre[RT_SEG][OUT_];
    __shared__ float accS[OUT_];
    const int b = blockIdx.x;
    const int tid = threadIdx.x;
    const float* cb = curo + (size_t)b * T_ * OUT_;

    const int o = tid % OUT_;
    const int sg = tid / OUT_;
    const float ao = 1.f / (1.f + expf(-tau_mo[o]));

    if (tid < RT_SEG * OUT_) {
        int t0 = sg * RT_LEN;
        int t1 = min(T_, t0 + RT_LEN);
        float u = 0.f, Ap = 1.f;
        for (int t = t0; t < t1; t++) {
            u = ao * u + (1.f - ao) * cb[t * OUT_ + o];
            Ap *= ao;
        }
        segU[sg][o] = u; segA[sg][o] = Ap;
    }
    if (tid < OUT_) accS[tid] = 0.f;
    __syncthreads();
    if (tid < OUT_) {
        float m = 0.f;
        for (int s = 0; s < RT_SEG; s++) {
            pre[s][tid] = m;
            m = segA[s][tid] * m + segU[s][tid];
        }
    }
    __syncthreads();
    if (tid < RT_SEG * OUT_) {
        int t0 = sg * RT_LEN;
        int t1 = min(T_, t0 + RT_LEN);
        float m = pre[sg][o];
        for (int t = t0; t < t1; t++) {
            m = ao * m + (1.f - ao) * cb[t * OUT_ + o];
            moS[t * OUT_ + o] = m;
        }
    }
    __syncthreads();
    if (tid >= WARM_ + 1 && tid < T_) {
        int t = tid;
        float mx = -3.0e38f;
#pragma unroll
        for (int o2 = 0; o2 < OUT_; o2++) mx = fmaxf(mx, moS[t * OUT_ + o2]);
        float es[OUT_]; float se = 0.f;
#pragma unroll
        for (int o2 = 0; o2 < OUT_; o2++) {
            float e = expf(moS[t * OUT_ + o2] - mx);
            es[o2] = e; se += e;
        }
        float inv = 1.f / se;
#pragma unroll
        for (int o2 = 0; o2 < OUT_; o2++) atomicAdd(&accS[o2], es[o2] * inv);
    }
    __syncthreads();
    if (tid < OUT_) out[(size_t)b * OUT_ + tid] = accS[tid];
}

extern "C" void kernel_launch(void* const* d_in, const int* in_sizes, int n_in,
                              void* d_out, int out_size, void* d_ws, size_t ws_size,
                              hipStream_t stream) {
    const float* x      = (const float*)d_in[0];
    const float* W1     = (const float*)d_in[1];
    const float* b1     = (const float*)d_in[2];
    const float* tau_m1 = (const float*)d_in[3];
    const float* tau_n1 = (const float*)d_in[4];
    const float* mask1  = (const float*)d_in[5];
    const float* W2     = (const float*)d_in[6];
    const float* b2     = (const float*)d_in[7];
    const float* tau_m2 = (const float*)d_in[8];
    const float* tau_n2 = (const float*)d_in[9];
    const float* mask2  = (const float*)d_in[10];
    const float* Wo     = (const float*)d_in[11];
    const float* bo     = (const float*)d_in[12];
    const float* tau_mo = (const float*)d_in[13];
    float* out = (float*)d_out;

    // ws-adaptive chunking. Single-chunk footprint ~367 MB (s1c/s2c aliased into xc),
    // 2x125 footprint ~216 MB, 100/100/50 ~176 MB.
    int ncs;  int tcs[3];
    bool single = (ws_size >= (size_t)368000000);
    if (single)                                { ncs = 1; tcs[0] = 250; }
    else if (ws_size >= (size_t)219000000)     { ncs = 2; tcs[0] = tcs[1] = 125; }
    else                                       { ncs = 3; tcs[0] = 100; tcs[1] = 100; tcs[2] = 50; }
    const int tcm = tcs[0];

    char* p = (char*)d_ws;
    auto alloc = [&](size_t bytes) { char* r = p; p += (bytes + 255) & ~(size_t)255; return r; };
    _Float16* w10 = (_Float16*)alloc((size_t)HB_ * INP_ * 2);
    _Float16* w11 = (_Float16*)alloc((size_t)HB_ * INP_ * 2);
    int8_t*   q2  = (int8_t*)alloc((size_t)HB_ * H_);
    int8_t*   q1  = (int8_t*)alloc((size_t)HB_ * H_);
    int8_t*   q0  = (int8_t*)alloc((size_t)HB_ * H_);
    _Float16* wo0 = (_Float16*)alloc((size_t)32 * H_ * 2);
    _Float16* wo1 = (_Float16*)alloc((size_t)32 * H_ * 2);
    _Float16* xc0 = (_Float16*)alloc((size_t)B_ * tcm * INP_ * 2);
    _Float16* xc1 = (_Float16*)alloc((size_t)B_ * tcm * INP_ * 2);
    int8_t*   s1c;
    _Float16* s2c;
    if (single) {  // xc planes are dead after l1_gemm; reuse them for spikes
        s1c = (int8_t*)xc0;        // needs 16 MB <= 45 MB
        s2c = (_Float16*)xc1;      // needs 33 MB <= 45 MB
    } else {
        s1c = (int8_t*)alloc((size_t)B_ * tcm * H_);
        s2c = (_Float16*)alloc((size_t)B_ * tcm * H_ * 2);
    }
    float* cur    = (float*)alloc((size_t)B_ * tcm * HB_ * 4);
    float* curo   = (float*)alloc((size_t)B_ * T_ * OUT_ * 4);
    float* st     = (float*)alloc((size_t)786432 * 4);
    float* d1  = st;
    float* m1  = d1 + (size_t)B_ * H_ * BR_;
    float* sp1 = m1 + (size_t)B_ * H_;
    float* d2  = sp1 + (size_t)B_ * H_;
    float* m2  = d2 + (size_t)B_ * H_ * BR_;
    float* sp2 = m2 + (size_t)B_ * H_;

    w1prep_kernel<<<(HB_ * INP_ + 255) / 256, 256, 0, stream>>>(W1, mask1, w10, w11);
    w2prep_kernel<<<(HB_ * H_ + 255) / 256, 256, 0, stream>>>(W2, mask2, q2, q1, q0);
    woprep_kernel<<<(32 * H_ + 255) / 256, 256, 0, stream>>>(Wo, wo0, wo1);
    zero_kernel<<<(786432 / 4 + 255) / 256, 256, 0, stream>>>(st, 786432 / 4);

    int t0 = 0;
    for (int c = 0; c < ncs; c++) {
        const int tc = tcs[c];
        const int M = B_ * tc;                 // multiple of 128
        dim3 gg(HB_ / 128, M / 128);           // n-fastest: x = n-tile, y = m-tile
        convx_kernel<<<(M * INP_ + 255) / 256, 256, 0, stream>>>(x, xc0, xc1, t0, tc, M * INP_);
        l1_gemm_kernel<<<gg, 256, 0, stream>>>(xc0, xc1, w10, w11, b1, cur);
        scan_i8_kernel<<<B_ * H_ / 256, 256, 0, stream>>>(cur, d1, m1, sp1, s1c, tau_m1, tau_n1, tc);
        mfma_i8_gemm_kernel<<<gg, 256, 0, stream>>>(s1c, q2, q1, q0, b2, cur);
        scan_f16_kernel<<<B_ * H_ / 256, 256, 0, stream>>>(cur, d2, m2, sp2, s2c, tau_m2, tau_n2, tc);
        rdot_mfma_kernel<<<M / 128, 256, 0, stream>>>(s2c, wo0, wo1, bo, curo, t0, tc);
        t0 += tc;
    }
    readout_kernel<<<B_, 256, 0, stream>>>(curo, tau_mo, out);
}

// Round 9
// 867.832 us; speedup vs baseline: 1.1389x; 1.1389x over previous
//
#include <hip/hip_runtime.h>
#include <math.h>
#include <stdint.h>

// Problem dims
#define B_    128
#define T_    250
#define IN_   700
#define INP_  704    // padded to 32
#define H_    512
#define OUT_  20
#define BR_   4
#define HB_   2048   // H_*BR_
#define WARM_ 10
#define VTH_  1.0f

typedef __attribute__((ext_vector_type(8)))  _Float16 half8;
typedef __attribute__((ext_vector_type(4)))  float f32x4;
typedef __attribute__((ext_vector_type(16))) float f32x16;
typedef __attribute__((ext_vector_type(4)))  int i32x4;
typedef __attribute__((ext_vector_type(16))) int i32x16;
typedef const __attribute__((address_space(1))) void* gptr_t;
typedef __attribute__((address_space(3))) void* lptr_t;

// ---------------- merged prep: w1 fp16 split | w2 i8 planes | wo fp16 split | state zero ----------
#define N1P_ (HB_ * INP_)     // 1441792
#define N2P_ (HB_ * H_)       // 1048576
#define N3P_ (32 * H_)        // 16384
#define N4P_ 196608           // state float4 count
__global__ __launch_bounds__(256)
void prep_kernel(const float* __restrict__ W1, const float* __restrict__ M1,
                 _Float16* __restrict__ w10, _Float16* __restrict__ w11,
                 const float* __restrict__ W2, const float* __restrict__ M2,
                 int8_t* __restrict__ q2, int8_t* __restrict__ q1, int8_t* __restrict__ q0,
                 const float* __restrict__ Wo, _Float16* __restrict__ wo0,
                 _Float16* __restrict__ wo1, float* __restrict__ st) {
    int i = blockIdx.x * 256 + threadIdx.x;
    if (i < N1P_) {
        int r = i / INP_, c = i - r * INP_;
        float v = (c < IN_) ? W1[(size_t)r * IN_ + c] * M1[(size_t)r * IN_ + c] : 0.f;
        _Float16 h0 = (_Float16)v;
        w10[i] = h0;
        w11[i] = (_Float16)(v - (float)h0);
        return;
    }
    i -= N1P_;
    if (i < N2P_) {
        float v = W2[i] * M2[i];
        int q = (int)lrintf(v * 67108864.f);              // |q| <= ~2.97e6
        int b0 = (int)(int8_t)(q & 0xFF);  q = (q - b0) >> 8;
        int b1 = (int)(int8_t)(q & 0xFF);  int b2 = (q - b1) >> 8;
        q0[i] = (int8_t)b0; q1[i] = (int8_t)b1; q2[i] = (int8_t)b2;
        return;
    }
    i -= N2P_;
    if (i < N3P_) {
        int n = i >> 9;
        float v = (n < OUT_) ? Wo[(size_t)n * H_ + (i & (H_ - 1))] : 0.f;
        _Float16 h0 = (_Float16)v;
        wo0[i] = h0;
        wo1[i] = (_Float16)(v - (float)h0);
        return;
    }
    i -= N3P_;
    if (i < N4P_) ((float4*)st)[i] = make_float4(0.f, 0.f, 0.f, 0.f);
}

// per-chunk x conversion: global rows (bb*T_+t0+tl) -> chunk-local [128*tc, INP_]
__global__ __launch_bounds__(256)
void convx_kernel(const float* __restrict__ x, _Float16* __restrict__ x0,
                  _Float16* __restrict__ x1, int t0, int tc, int ntot) {
    int i = blockIdx.x * 256 + threadIdx.x;
    if (i >= ntot) return;
    int r = i / INP_, c = i - r * INP_;
    int bb = r / tc, tl = r - bb * tc;
    float v = (c < IN_) ? x[((size_t)bb * T_ + t0 + tl) * IN_ + c] : 0.f;
    _Float16 h0 = (_Float16)v;
    x0[i] = h0;
    x1[i] = (_Float16)(v - (float)h0);
}

// ---------------- L1 GEMM: 32x32x16 f16 MFMA, XCD-aware flat grid ----------------
// flat grid 16*mtiles; xcd = L&7 owns n-tiles {2*xcd, 2*xcd+1} (weights L2-resident),
// sweeps m. local = L>>3: n = 2*xcd + (local&1), m = local>>1.
__global__ __launch_bounds__(256)
void l1_gemm_kernel(const _Float16* __restrict__ x0, const _Float16* __restrict__ x1,
                    const _Float16* __restrict__ w0, const _Float16* __restrict__ w1,
                    const float* __restrict__ bias, float* __restrict__ C) {
    __shared__ alignas(16) _Float16 A0s[128 * 32];
    __shared__ alignas(16) _Float16 A1s[128 * 32];
    __shared__ alignas(16) _Float16 B0s[128 * 32];
    __shared__ alignas(16) _Float16 B1s[128 * 32];
    const int tid  = threadIdx.x;
    const int wave = tid >> 6, lane = tid & 63;
    const int L = blockIdx.x;
    const int xcd = L & 7, local = L >> 3;
    const int bn = (2 * xcd + (local & 1)) * 128;
    const int bm = (local >> 1) * 128;

    const int    srow  = tid >> 2;
    const int    skoff = (tid & 3) * 8;
    const size_t aoff0 = (size_t)(bm + srow) * INP_ + skoff;
    const size_t aoff1 = aoff0 + (size_t)64 * INP_;
    const size_t boff0 = (size_t)(bn + srow) * INP_ + skoff;
    const size_t boff1 = boff0 + (size_t)64 * INP_;
    const int lo0 = wave * 512, lo1 = 2048 + wave * 512;

    const int wm = wave & 1, wn = wave >> 1;
    const int row = lane & 31;           // row/col within 32-tile
    const int kh  = (lane >> 5) * 8;     // k-offset (halfs) within 16-K step

    f32x16 acc[2][2] = {};

    for (int kt = 0; kt < INP_ / 32; kt++) {
        const int k0 = kt * 32;
        __builtin_amdgcn_global_load_lds((gptr_t)(x0 + aoff0 + k0), (lptr_t)(A0s + lo0), 16, 0, 0);
        __builtin_amdgcn_global_load_lds((gptr_t)(x0 + aoff1 + k0), (lptr_t)(A0s + lo1), 16, 0, 0);
        __builtin_amdgcn_global_load_lds((gptr_t)(x1 + aoff0 + k0), (lptr_t)(A1s + lo0), 16, 0, 0);
        __builtin_amdgcn_global_load_lds((gptr_t)(x1 + aoff1 + k0), (lptr_t)(A1s + lo1), 16, 0, 0);
        __builtin_amdgcn_global_load_lds((gptr_t)(w0 + boff0 + k0), (lptr_t)(B0s + lo0), 16, 0, 0);
        __builtin_amdgcn_global_load_lds((gptr_t)(w0 + boff1 + k0), (lptr_t)(B0s + lo1), 16, 0, 0);
        __builtin_amdgcn_global_load_lds((gptr_t)(w1 + boff0 + k0), (lptr_t)(B1s + lo0), 16, 0, 0);
        __builtin_amdgcn_global_load_lds((gptr_t)(w1 + boff1 + k0), (lptr_t)(B1s + lo1), 16, 0, 0);
        __syncthreads();

        half8 a0f[2][2], a1f[2][2], b0f[2][2], b1f[2][2];   // [tile][kstep]
#pragma unroll
        for (int mt = 0; mt < 2; mt++)
#pragma unroll
            for (int ks = 0; ks < 2; ks++)
                a0f[mt][ks] = *(const half8*)&A0s[(wm * 64 + mt * 32 + row) * 32 + ks * 16 + kh];
#pragma unroll
        for (int nt = 0; nt < 2; nt++)
#pragma unroll
            for (int ks = 0; ks < 2; ks++)
                b0f[nt][ks] = *(const half8*)&B0s[(wn * 64 + nt * 32 + row) * 32 + ks * 16 + kh];
#pragma unroll
        for (int ks = 0; ks < 2; ks++)
#pragma unroll
            for (int mt = 0; mt < 2; mt++)
#pragma unroll
                for (int nt = 0; nt < 2; nt++)
                    acc[mt][nt] = __builtin_amdgcn_mfma_f32_32x32x16_f16(
                        a0f[mt][ks], b0f[nt][ks], acc[mt][nt], 0, 0, 0);
#pragma unroll
        for (int nt = 0; nt < 2; nt++)
#pragma unroll
            for (int ks = 0; ks < 2; ks++)
                b1f[nt][ks] = *(const half8*)&B1s[(wn * 64 + nt * 32 + row) * 32 + ks * 16 + kh];
#pragma unroll
        for (int ks = 0; ks < 2; ks++)
#pragma unroll
            for (int mt = 0; mt < 2; mt++)
#pragma unroll
                for (int nt = 0; nt < 2; nt++)
                    acc[mt][nt] = __builtin_amdgcn_mfma_f32_32x32x16_f16(
                        a0f[mt][ks], b1f[nt][ks], acc[mt][nt], 0, 0, 0);
#pragma unroll
        for (int mt = 0; mt < 2; mt++)
#pragma unroll
            for (int ks = 0; ks < 2; ks++)
                a1f[mt][ks] = *(const half8*)&A1s[(wm * 64 + mt * 32 + row) * 32 + ks * 16 + kh];
#pragma unroll
        for (int ks = 0; ks < 2; ks++)
#pragma unroll
            for (int mt = 0; mt < 2; mt++)
#pragma unroll
                for (int nt = 0; nt < 2; nt++)
                    acc[mt][nt] = __builtin_amdgcn_mfma_f32_32x32x16_f16(
                        a1f[mt][ks], b0f[nt][ks], acc[mt][nt], 0, 0, 0);
        __syncthreads();
    }

    // C/D: col=lane&31, row=(reg&3)+8*(reg>>2)+4*(lane>>5)
    const int col = lane & 31;
    const int rb  = 4 * (lane >> 5);
#pragma unroll
    for (int nt = 0; nt < 2; nt++) {
        const int gc = bn + wn * 64 + nt * 32 + col;
        const float bv = bias[gc];
#pragma unroll
        for (int mt = 0; mt < 2; mt++) {
#pragma unroll
            for (int reg = 0; reg < 16; reg++) {
                const int gr = bm + wm * 64 + mt * 32 + (reg & 3) + 8 * (reg >> 2) + rb;
                C[(size_t)gr * HB_ + gc] = acc[mt][nt][reg] + bv;
            }
        }
    }
}

// ---------------- i8 GEMM (layer 2): 32x32x32, XCD-aware flat grid, exact Horner ----------------
__global__ __launch_bounds__(256)
void mfma_i8_gemm_kernel(const int8_t* __restrict__ A,
                         const int8_t* __restrict__ p2, const int8_t* __restrict__ p1,
                         const int8_t* __restrict__ p0,
                         const float* __restrict__ bias, float* __restrict__ C) {
    __shared__ alignas(16) int8_t As[128 * 64];   // 8 KB, K-tile 64
    __shared__ alignas(16) int8_t Bs[128 * 64];
    const int tid  = threadIdx.x;
    const int wave = tid >> 6, lane = tid & 63;
    const int L = blockIdx.x;
    const int xcd = L & 7, local = L >> 3;
    const int bn = (2 * xcd + (local & 1)) * 128;
    const int bm = (local >> 1) * 128;

    const int    srow  = tid >> 2;
    const int    skoff = (tid & 3) * 16;
    const size_t aoff0 = (size_t)(bm + srow) * H_ + skoff;
    const size_t aoff1 = aoff0 + (size_t)64 * H_;
    const size_t boff0 = (size_t)(bn + srow) * H_ + skoff;
    const size_t boff1 = boff0 + (size_t)64 * H_;
    lptr_t lA0 = (lptr_t)(As + wave * 1024);
    lptr_t lA1 = (lptr_t)(As + 4096 + wave * 1024);
    lptr_t lB0 = (lptr_t)(Bs + wave * 1024);
    lptr_t lB1 = (lptr_t)(Bs + 4096 + wave * 1024);

    const int wm = wave & 1, wn = wave >> 1;
    const int row = lane & 31;
    const int kb  = (lane >> 5) * 16;   // byte offset within 32-K step

    const int8_t* planes[3] = {p2, p1, p0};
    i32x16 acc[2][2] = {};

#pragma unroll
    for (int s = 0; s < 3; s++) {
        if (s) {
#pragma unroll
            for (int mt = 0; mt < 2; mt++)
#pragma unroll
                for (int nt = 0; nt < 2; nt++) acc[mt][nt] *= 256;  // exact, |acc|<1.6e9
        }
        const int8_t* pw = planes[s];
        for (int kt = 0; kt < H_ / 64; kt++) {
            const int k0 = kt * 64;
            __builtin_amdgcn_global_load_lds((gptr_t)(A  + aoff0 + k0), lA0, 16, 0, 0);
            __builtin_amdgcn_global_load_lds((gptr_t)(A  + aoff1 + k0), lA1, 16, 0, 0);
            __builtin_amdgcn_global_load_lds((gptr_t)(pw + boff0 + k0), lB0, 16, 0, 0);
            __builtin_amdgcn_global_load_lds((gptr_t)(pw + boff1 + k0), lB1, 16, 0, 0);
            __syncthreads();

            i32x4 af[2][2], bf[2][2];
#pragma unroll
            for (int mt = 0; mt < 2; mt++)
#pragma unroll
                for (int ks = 0; ks < 2; ks++)
                    af[mt][ks] = *(const i32x4*)&As[(wm * 64 + mt * 32 + row) * 64 + ks * 32 + kb];
#pragma unroll
            for (int nt = 0; nt < 2; nt++)
#pragma unroll
                for (int ks = 0; ks < 2; ks++)
                    bf[nt][ks] = *(const i32x4*)&Bs[(wn * 64 + nt * 32 + row) * 64 + ks * 32 + kb];
#pragma unroll
            for (int ks = 0; ks < 2; ks++)
#pragma unroll
                for (int mt = 0; mt < 2; mt++)
#pragma unroll
                    for (int nt = 0; nt < 2; nt++)
                        acc[mt][nt] = __builtin_amdgcn_mfma_i32_32x32x32_i8(
                            af[mt][ks], bf[nt][ks], acc[mt][nt], 0, 0, 0);
            __syncthreads();
        }
    }

    const float scale = 1.f / 67108864.f;
    const int col = lane & 31;
    const int rb  = 4 * (lane >> 5);
#pragma unroll
    for (int nt = 0; nt < 2; nt++) {
        const int gc = bn + wn * 64 + nt * 32 + col;
        const float bv = bias[gc];
#pragma unroll
        for (int mt = 0; mt < 2; mt++) {
#pragma unroll
            for (int reg = 0; reg < 16; reg++) {
                const int gr = bm + wm * 64 + mt * 32 + (reg & 3) + 8 * (reg >> 2) + rb;
                C[(size_t)gr * HB_ + gc] = (float)acc[mt][nt][reg] * scale + bv;
            }
        }
    }
}

// ---------------- per-(b,h) LIF scans over a time chunk (chunk-local I/O) ----------------
#define SCAN_BODY(SPIKE_STORE)                                                  \
    int idx = blockIdx.x * 256 + threadIdx.x;                                   \
    int b = idx >> 9;                                                           \
    int h = idx & (H_ - 1);                                                     \
    float alpha = 1.f / (1.f + expf(-tau_m[h]));                                \
    float4 tn = ((const float4*)tau_n)[h];                                      \
    float4 beta;                                                                \
    beta.x = 1.f / (1.f + expf(-tn.x));                                         \
    beta.y = 1.f / (1.f + expf(-tn.y));                                         \
    beta.z = 1.f / (1.f + expf(-tn.z));                                         \
    beta.w = 1.f / (1.f + expf(-tn.w));                                         \
    float4 d = ((const float4*)dst)[idx];                                       \
    float m = mst[idx];                                                         \
    float sp = spst[idx];                                                       \
    const float* cp = cur + (size_t)b * tc * HB_ + h * BR_;                     \
    for (int t = 0; t < tc; t++) {                                              \
        float4 c = *(const float4*)cp;                                          \
        cp += HB_;                                                              \
        d.x = beta.x * d.x + (1.f - beta.x) * c.x;                              \
        d.y = beta.y * d.y + (1.f - beta.y) * c.y;                              \
        d.z = beta.z * d.z + (1.f - beta.z) * c.z;                              \
        d.w = beta.w * d.w + (1.f - beta.w) * c.w;                              \
        float s4 = ((d.x + d.y) + d.z) + d.w;                                   \
        m = m * alpha + (1.f - alpha) * s4 - VTH_ * sp;                         \
        sp = (m > VTH_) ? 1.f : 0.f;                                            \
        SPIKE_STORE;                                                            \
    }                                                                           \
    ((float4*)dst)[idx] = d;                                                    \
    mst[idx] = m;                                                               \
    spst[idx] = sp;

__global__ __launch_bounds__(256)
void scan_i8_kernel(const float* __restrict__ cur, float* __restrict__ dst,
                    float* __restrict__ mst, float* __restrict__ spst,
                    int8_t* __restrict__ sout, const float* __restrict__ tau_m,
                    const float* __restrict__ tau_n, int tc) {
    SCAN_BODY(sout[((size_t)b * tc + t) * H_ + h] = (int8_t)(m > VTH_))
}

__global__ __launch_bounds__(256)
void scan_f16_kernel(const float* __restrict__ cur, float* __restrict__ dst,
                     float* __restrict__ mst, float* __restrict__ spst,
                     _Float16* __restrict__ sout, const float* __restrict__ tau_m,
                     const float* __restrict__ tau_n, int tc) {
    SCAN_BODY(sout[((size_t)b * tc + t) * H_ + h] = (_Float16)sp)
}

// ---------------- readout GEMM (MFMA 16x16): curo[b,t,o] = s2c . (wo0+wo1)^T + bo ----------------
__global__ __launch_bounds__(256)
void rdot_mfma_kernel(const _Float16* __restrict__ s2c, const _Float16* __restrict__ wo0,
                      const _Float16* __restrict__ wo1, const float* __restrict__ bo,
                      float* __restrict__ curo, int t0, int tc) {
    __shared__ alignas(16) _Float16 As[128 * 32];   // 8 KB
    __shared__ alignas(16) _Float16 B0s[32 * 32];   // 2 KB
    __shared__ alignas(16) _Float16 B1s[32 * 32];
    const int tid  = threadIdx.x;
    const int wave = tid >> 6, lane = tid & 63;
    const int bm = blockIdx.x * 128;

    const int    srow  = tid >> 2;
    const int    skoff = (tid & 3) * 8;
    const size_t aoff0 = (size_t)(bm + srow) * H_ + skoff;
    const size_t aoff1 = aoff0 + (size_t)64 * H_;
    lptr_t lA0 = (lptr_t)(As + wave * 512);
    lptr_t lA1 = (lptr_t)(As + 2048 + wave * 512);
    const _Float16* bsrc = (wave < 2) ? wo0 : wo1;
    const int bw = wave & 1;
    const size_t boff = (size_t)(bw * 16 + (lane >> 2)) * H_ + (lane & 3) * 8;
    lptr_t lB = (lptr_t)(((wave < 2) ? B0s : B1s) + bw * 512);

    const int fr = lane & 15;
    const int fk = (lane >> 4) * 8;

    f32x4 acc[2][2] = {};

    for (int kt = 0; kt < H_ / 32; kt++) {
        const int k0 = kt * 32;
        __builtin_amdgcn_global_load_lds((gptr_t)(s2c + aoff0 + k0), lA0, 16, 0, 0);
        __builtin_amdgcn_global_load_lds((gptr_t)(s2c + aoff1 + k0), lA1, 16, 0, 0);
        __builtin_amdgcn_global_load_lds((gptr_t)(bsrc + boff + k0), lB, 16, 0, 0);
        __syncthreads();

        half8 af[2], b0[2], b1[2];
#pragma unroll
        for (int mi = 0; mi < 2; mi++)
            af[mi] = *(const half8*)&As[(wave * 32 + mi * 16 + fr) * 32 + fk];
#pragma unroll
        for (int ni = 0; ni < 2; ni++) {
            b0[ni] = *(const half8*)&B0s[(ni * 16 + fr) * 32 + fk];
            b1[ni] = *(const half8*)&B1s[(ni * 16 + fr) * 32 + fk];
        }
#pragma unroll
        for (int mi = 0; mi < 2; mi++)
#pragma unroll
            for (int ni = 0; ni < 2; ni++) {
                acc[mi][ni] = __builtin_amdgcn_mfma_f32_16x16x32_f16(af[mi], b0[ni], acc[mi][ni], 0, 0, 0);
                acc[mi][ni] = __builtin_amdgcn_mfma_f32_16x16x32_f16(af[mi], b1[ni], acc[mi][ni], 0, 0, 0);
            }
        __syncthreads();
    }

    const int cc = lane & 15;
    const int cr = (lane >> 4) * 4;
#pragma unroll
    for (int ni = 0; ni < 2; ni++) {
        const int gc = ni * 16 + cc;
        if (gc < OUT_) {
            const float bv = bo[gc];
#pragma unroll
            for (int mi = 0; mi < 2; mi++) {
#pragma unroll
                for (int r = 0; r < 4; r++) {
                    const int gr = bm + wave * 32 + mi * 16 + cr + r;
                    const int bb = gr / tc, tl = gr - bb * tc;
                    curo[((size_t)bb * T_ + t0 + tl) * OUT_ + gc] = acc[mi][ni][r] + bv;
                }
            }
        }
    }
}

// ---------------- parallel readout: segmented scan + t-parallel softmax-sum ----------------
#define RT_SEG 12
#define RT_LEN 21   // 12*21 = 252 >= 250

__global__ __launch_bounds__(256)
void readout_kernel(const float* __restrict__ curo, const float* __restrict__ tau_mo,
                    float* __restrict__ out) {
    __shared__ float moS[T_ * OUT_];          // 20 KB
    __shared__ float segA[RT_SEG][OUT_];
    __shared__ float segU[RT_SEG][OUT_];
    __shared__ float pre[RT_SEG][OUT_];
    __shared__ float accS[OUT_];
    const int b = blockIdx.x;
    const int tid = threadIdx.x;
    const float* cb = curo + (size_t)b * T_ * OUT_;

    const int o = tid % OUT_;
    const int sg = tid / OUT_;
    const float ao = 1.f / (1.f + expf(-tau_mo[o]));

    if (tid < RT_SEG * OUT_) {
        int t0 = sg * RT_LEN;
        int t1 = min(T_, t0 + RT_LEN);
        float u = 0.f, Ap = 1.f;
        for (int t = t0; t < t1; t++) {
            u = ao * u + (1.f - ao) * cb[t * OUT_ + o];
            Ap *= ao;
        }
        segU[sg][o] = u; segA[sg][o] = Ap;
    }
    if (tid < OUT_) accS[tid] = 0.f;
    __syncthreads();
    if (tid < OUT_) {
        float m = 0.f;
        for (int s = 0; s < RT_SEG; s++) {
            pre[s][tid] = m;
            m = segA[s][tid] * m + segU[s][tid];
        }
    }
    __syncthreads();
    if (tid < RT_SEG * OUT_) {
        int t0 = sg * RT_LEN;
        int t1 = min(T_, t0 + RT_LEN);
        float m = pre[sg][o];
        for (int t = t0; t < t1; t++) {
            m = ao * m + (1.f - ao) * cb[t * OUT_ + o];
            moS[t * OUT_ + o] = m;
        }
    }
    __syncthreads();
    if (tid >= WARM_ + 1 && tid < T_) {
        int t = tid;
        float mx = -3.0e38f;
#pragma unroll
        for (int o2 = 0; o2 < OUT_; o2++) mx = fmaxf(mx, moS[t * OUT_ + o2]);
        float es[OUT_]; float se = 0.f;
#pragma unroll
        for (int o2 = 0; o2 < OUT_; o2++) {
            float e = expf(moS[t * OUT_ + o2] - mx);
            es[o2] = e; se += e;
        }
        float inv = 1.f / se;
#pragma unroll
        for (int o2 = 0; o2 < OUT_; o2++) atomicAdd(&accS[o2], es[o2] * inv);
    }
    __syncthreads();
    if (tid < OUT_) out[(size_t)b * OUT_ + tid] = accS[tid];
}

extern "C" void kernel_launch(void* const* d_in, const int* in_sizes, int n_in,
                              void* d_out, int out_size, void* d_ws, size_t ws_size,
                              hipStream_t stream) {
    const float* x      = (const float*)d_in[0];
    const float* W1     = (const float*)d_in[1];
    const float* b1     = (const float*)d_in[2];
    const float* tau_m1 = (const float*)d_in[3];
    const float* tau_n1 = (const float*)d_in[4];
    const float* mask1  = (const float*)d_in[5];
    const float* W2     = (const float*)d_in[6];
    const float* b2     = (const float*)d_in[7];
    const float* tau_m2 = (const float*)d_in[8];
    const float* tau_n2 = (const float*)d_in[9];
    const float* mask2  = (const float*)d_in[10];
    const float* Wo     = (const float*)d_in[11];
    const float* bo     = (const float*)d_in[12];
    const float* tau_mo = (const float*)d_in[13];
    float* out = (float*)d_out;

    // ws-adaptive chunking. Single-chunk footprint ~367 MB (s1c/s2c aliased into xc),
    // 2x125 footprint ~216 MB, 100/100/50 ~176 MB.
    int ncs;  int tcs[3];
    bool single = (ws_size >= (size_t)368000000);
    if (single)                                { ncs = 1; tcs[0] = 250; }
    else if (ws_size >= (size_t)219000000)     { ncs = 2; tcs[0] = tcs[1] = 125; }
    else                                       { ncs = 3; tcs[0] = 100; tcs[1] = 100; tcs[2] = 50; }
    const int tcm = tcs[0];

    char* p = (char*)d_ws;
    auto alloc = [&](size_t bytes) { char* r = p; p += (bytes + 255) & ~(size_t)255; return r; };
    _Float16* w10 = (_Float16*)alloc((size_t)HB_ * INP_ * 2);
    _Float16* w11 = (_Float16*)alloc((size_t)HB_ * INP_ * 2);
    int8_t*   q2  = (int8_t*)alloc((size_t)HB_ * H_);
    int8_t*   q1  = (int8_t*)alloc((size_t)HB_ * H_);
    int8_t*   q0  = (int8_t*)alloc((size_t)HB_ * H_);
    _Float16* wo0 = (_Float16*)alloc((size_t)32 * H_ * 2);
    _Float16* wo1 = (_Float16*)alloc((size_t)32 * H_ * 2);
    _Float16* xc0 = (_Float16*)alloc((size_t)B_ * tcm * INP_ * 2);
    _Float16* xc1 = (_Float16*)alloc((size_t)B_ * tcm * INP_ * 2);
    int8_t*   s1c;
    _Float16* s2c;
    if (single) {  // xc planes are dead after l1_gemm; reuse them for spikes
        s1c = (int8_t*)xc0;        // needs 16 MB <= 45 MB
        s2c = (_Float16*)xc1;      // needs 33 MB <= 45 MB
    } else {
        s1c = (int8_t*)alloc((size_t)B_ * tcm * H_);
        s2c = (_Float16*)alloc((size_t)B_ * tcm * H_ * 2);
    }
    float* cur    = (float*)alloc((size_t)B_ * tcm * HB_ * 4);
    float* curo   = (float*)alloc((size_t)B_ * T_ * OUT_ * 4);
    float* st     = (float*)alloc((size_t)786432 * 4);
    float* d1  = st;
    float* m1  = d1 + (size_t)B_ * H_ * BR_;
    float* sp1 = m1 + (size_t)B_ * H_;
    float* d2  = sp1 + (size_t)B_ * H_;
    float* m2  = d2 + (size_t)B_ * H_ * BR_;
    float* sp2 = m2 + (size_t)B_ * H_;

    // single merged prep (w1 split + w2 i8 + wo split + state zero)
    prep_kernel<<<(N1P_ + N2P_ + N3P_ + N4P_) / 256, 256, 0, stream>>>(
        W1, mask1, w10, w11, W2, mask2, q2, q1, q0, Wo, wo0, wo1, st);

    int t0 = 0;
    for (int c = 0; c < ncs; c++) {
        const int tc = tcs[c];
        const int M = B_ * tc;                 // multiple of 128
        const int nblk = (HB_ / 128) * (M / 128);   // flat XCD-aware grid
        convx_kernel<<<(M * INP_ + 255) / 256, 256, 0, stream>>>(x, xc0, xc1, t0, tc, M * INP_);
        l1_gemm_kernel<<<nblk, 256, 0, stream>>>(xc0, xc1, w10, w11, b1, cur);
        scan_i8_kernel<<<B_ * H_ / 256, 256, 0, stream>>>(cur, d1, m1, sp1, s1c, tau_m1, tau_n1, tc);
        mfma_i8_gemm_kernel<<<nblk, 256, 0, stream>>>(s1c, q2, q1, q0, b2, cur);
        scan_f16_kernel<<<B_ * H_ / 256, 256, 0, stream>>>(cur, d2, m2, sp2, s2c, tau_m2, tau_n2, tc);
        rdot_mfma_kernel<<<M / 128, 256, 0, stream>>>(s2c, wo0, wo1, bo, curo, t0, tc);
        t0 += tc;
    }
    readout_kernel<<<B_, 256, 0, stream>>>(curo, tau_mo, out);
}